// Round 8
// baseline (542.434 us; speedup 1.0000x reference)
//
#include <hip/hip_runtime.h>

#define EMB 32
#define BSHIFT 10
#define RPB 1024           // rows per bucket
#define NB 256             // max buckets
#define TILE 4096
#define PT_THREADS 256
#define PT_ITEMS 16
#define SP_THREADS 1024
#define COLMASK 0x3FFFF    // 18 bits col (n <= 262144); lrow in bits 18..27

// ---------------- CSR build ----------------

__global__ void bucket_hist_kernel(const int* __restrict__ rows, int nnz,
                                   int* __restrict__ bhist, int nb) {
    __shared__ int h[NB];
    int t = threadIdx.x;
    h[t] = 0;
    __syncthreads();
    int stride = gridDim.x * blockDim.x;
    for (int i = blockIdx.x * blockDim.x + t; i < nnz; i += stride)
        atomicAdd(&h[rows[i] >> BSHIFT], 1);
    __syncthreads();
    if (t < nb && h[t] > 0) atomicAdd(&bhist[t], h[t]);
}

// Tile-wise partition into bucket-grouped (val, col|lrow<<18) + lrow sidecar.
// (unchanged from R6 — measured working)
__global__ __launch_bounds__(PT_THREADS) void partition_kernel(
        const float* __restrict__ vals, const int* __restrict__ rows,
        const int* __restrict__ cols, int nnz,
        const int* __restrict__ bhist, int* __restrict__ cursor,
        int2* __restrict__ pairs_stage, unsigned short* __restrict__ lrow_stage) {
    __shared__ int locbase[NB];
    __shared__ int h[NB];
    __shared__ int sc[NB];
    __shared__ int delta[NB];
    __shared__ float s_val[TILE];
    __shared__ int s_pack[TILE];
    __shared__ unsigned short s_bkt[TILE];
    const int t = threadIdx.x;
    const int tile_start = blockIdx.x * TILE;
    const int tile_cnt = min(TILE, nnz - tile_start);

    const int ownb = bhist[t];
    locbase[t] = ownb;
    h[t] = 0;
    __syncthreads();
    for (int off = 1; off < NB; off <<= 1) {
        int add = (t >= off) ? locbase[t - off] : 0;
        __syncthreads();
        locbase[t] += add;
        __syncthreads();
    }
    const int eb = locbase[t] - ownb;

    float v[PT_ITEMS];
    int pk[PT_ITEMS], b[PT_ITEMS];
    #pragma unroll
    for (int k = 0; k < PT_ITEMS; ++k) {
        int i = tile_start + t + k * PT_THREADS;
        if (i < nnz) {
            int r = rows[i];
            v[k] = vals[i];
            pk[k] = cols[i] | ((r & (RPB - 1)) << 18);
            b[k] = r >> BSHIFT;
            atomicAdd(&h[b[k]], 1);
        } else {
            b[k] = -1;
        }
    }
    __syncthreads();
    const int own = h[t];
    sc[t] = own;
    __syncthreads();
    for (int off = 1; off < NB; off <<= 1) {
        int add = (t >= off) ? sc[t - off] : 0;
        __syncthreads();
        sc[t] += add;
        __syncthreads();
    }
    const int excl = sc[t] - own;
    if (own > 0) {
        int old = atomicAdd(&cursor[t], own);
        delta[t] = (eb + old) - excl;
    }
    h[t] = excl;
    __syncthreads();
    #pragma unroll
    for (int k = 0; k < PT_ITEMS; ++k) {
        if (b[k] >= 0) {
            int rank = atomicAdd(&h[b[k]], 1);
            s_val[rank] = v[k];
            s_pack[rank] = pk[k];
            s_bkt[rank] = (unsigned short)b[k];
        }
    }
    __syncthreads();
    for (int i = t; i < tile_cnt; i += PT_THREADS) {
        int bb = s_bkt[i];
        int gpos = delta[bb] + i;
        int pk_i = s_pack[i];
        pairs_stage[gpos] = make_int2(__float_as_int(s_val[i]), pk_i);
        lrow_stage[gpos] = (unsigned short)(((unsigned)pk_i) >> 18);
    }
}

// Per-bucket counting sort + LENGTH-SORTED slot assignment.
// Emits: rps[slot] (pair range per sorted slot), order[slot] (original row or -1),
// and pairs[] written in sorted-slot-contiguous order (col stripped of lrow).
__global__ __launch_bounds__(SP_THREADS) void bucket_sort_kernel(
        const int2* __restrict__ pairs_stage, const unsigned short* __restrict__ lrow_stage,
        const int* __restrict__ bhist, int n, int nnz, int nb,
        int* __restrict__ rps, int* __restrict__ order, int2* __restrict__ pairs) {
    __shared__ int rh[RPB];                 // per-row nnz count (kept intact)
    __shared__ int pre[RPB];                // sorted-length prefix workspace
    __shared__ int rc[RPB];                 // per original local row write cursor
    __shared__ unsigned short srOf[RPB];    // row t -> sorted slot
    __shared__ unsigned short tOf[RPB];     // sorted slot -> row t
    __shared__ int binCnt[66];
    __shared__ int binBase[66];
    const int bkt = blockIdx.x;
    const int t = threadIdx.x;

    // bucket pair-range via scan of bhist
    if (t < NB) rh[t] = bhist[t];
    __syncthreads();
    for (int off = 1; off < NB; off <<= 1) {
        int add = (t < NB && t >= off) ? rh[t - off] : 0;
        __syncthreads();
        if (t < NB) rh[t] += add;
        __syncthreads();
    }
    const int i0 = (bkt > 0) ? rh[bkt - 1] : 0;
    const int i1 = rh[bkt];
    __syncthreads();

    const int row0 = bkt << BSHIFT;
    const int nrows = min(RPB, n - row0);
    rh[t] = 0;
    if (t < 66) binCnt[t] = 0;
    __syncthreads();
    for (int i = i0 + t; i < i1; i += SP_THREADS)
        atomicAdd(&rh[lrow_stage[i]], 1);
    __syncthreads();
    const int own = rh[t];                 // nnz of local row t (0 for t>=nrows)
    const bool valid = t < nrows;
    const int bin = valid ? min(own, 63) : 65 - 1;  // invalid rows -> bin 64
    const int rb = atomicAdd(&binCnt[bin], 1);
    __syncthreads();
    if (t == 0) {
        int s = 0;
        for (int k = 0; k < 65; ++k) { binBase[k] = s; s += binCnt[k]; }
    }
    __syncthreads();
    const int sr = binBase[bin] + rb;      // sorted slot for row t (bijection)
    srOf[t] = (unsigned short)sr;
    tOf[sr] = (unsigned short)t;
    pre[sr] = valid ? own : 0;             // sorted lengths
    __syncthreads();
    // inclusive scan of pre[] over 1024 slots
    for (int off = 1; off < RPB; off <<= 1) {
        int add = (t >= off) ? pre[t - off] : 0;
        __syncthreads();
        pre[t] += add;
        __syncthreads();
    }
    // slot t outputs (rh[] still holds per-row counts)
    const int tt = tOf[t];
    const int lenSlot = rh[tt];
    const int startSlot = pre[t] - lenSlot;        // exclusive prefix
    const int gslot = (bkt << BSHIFT) + t;
    rps[gslot] = i0 + startSlot;
    order[gslot] = (tt < nrows) ? (row0 + tt) : -1;
    if (bkt == nb - 1 && t == 0) rps[nb << BSHIFT] = nnz;
    __syncthreads();
    // per-row write cursor: start of row t's sorted slot
    rc[t] = i0 + (pre[srOf[t]] - rh[t]);
    __syncthreads();
    for (int i = i0 + t; i < i1; i += SP_THREADS) {
        int2 p = pairs_stage[i];
        int r = lrow_stage[i];
        int pos = atomicAdd(&rc[r], 1);
        pairs[pos] = make_int2(p.x, p.y & COLMASK);
    }
}

// ---------------- misc ----------------

__global__ void softmax4_kernel(const float* __restrict__ alpha, float* __restrict__ coefs) {
    if (threadIdx.x == 0 && blockIdx.x == 0) {
        float m = fmaxf(fmaxf(alpha[0], alpha[1]), fmaxf(alpha[2], alpha[3]));
        float e0 = __expf(alpha[0] - m), e1 = __expf(alpha[1] - m);
        float e2 = __expf(alpha[2] - m), e3 = __expf(alpha[3] - m);
        float inv = 1.0f / (e0 + e1 + e2 + e3);
        coefs[0] = e0 * inv; coefs[1] = e1 * inv; coefs[2] = e2 * inv; coefs[3] = e3 * inv;
    }
}

// ---------------- SpMM: 2 sorted rows per 8-lane group, 8 gathers in flight ----------------

template <bool INIT, bool STORE_E>
__global__ __launch_bounds__(256) void spmm_kernel(
        const int* __restrict__ rps, const int* __restrict__ order,
        const int2* __restrict__ pairs, const float* __restrict__ X,
        float* __restrict__ Eout, float* __restrict__ Efin,
        const float* __restrict__ coefs, int hop, int nslots) {
    const int tid = blockIdx.x * blockDim.x + threadIdx.x;
    const int g = tid >> 3;
    const int slotA = g * 2, slotB = g * 2 + 1;
    if (slotA >= nslots) return;
    const int sub = (tid & 7) * 4;
    int jA = rps[slotA];
    const int eA = rps[slotA + 1];
    const bool hasB = slotB < nslots;
    int jB = hasB ? rps[slotB] : 0;
    const int eB = hasB ? rps[slotB + 1] : 0;
    const int rowA = order[slotA];
    const int rowB = hasB ? order[slotB] : -1;

    float aAx = 0.f, aAy = 0.f, aAz = 0.f, aAw = 0.f;
    float aBx = 0.f, aBy = 0.f, aBz = 0.f, aBw = 0.f;

    auto scal = [&](int j, float& x_, float& y_, float& z_, float& w_) {
        int2 p = pairs[j];
        float v = __int_as_float(p.x);
        const float4 x = *reinterpret_cast<const float4*>(X + (size_t)p.y * EMB + sub);
        x_ = fmaf(v, x.x, x_); y_ = fmaf(v, x.y, y_);
        z_ = fmaf(v, x.z, z_); w_ = fmaf(v, x.w, w_);
    };
    auto quad = [&](int j, float& x_, float& y_, float& z_, float& w_) {
        const int4 pa = *reinterpret_cast<const int4*>(pairs + j);
        const int4 pb = *reinterpret_cast<const int4*>(pairs + j + 2);
        const float4 x0 = *reinterpret_cast<const float4*>(X + (size_t)pa.y * EMB + sub);
        const float4 x1 = *reinterpret_cast<const float4*>(X + (size_t)pa.w * EMB + sub);
        const float4 x2 = *reinterpret_cast<const float4*>(X + (size_t)pb.y * EMB + sub);
        const float4 x3 = *reinterpret_cast<const float4*>(X + (size_t)pb.w * EMB + sub);
        const float v0 = __int_as_float(pa.x), v1 = __int_as_float(pa.z);
        const float v2 = __int_as_float(pb.x), v3 = __int_as_float(pb.z);
        x_ = fmaf(v0, x0.x, x_); y_ = fmaf(v0, x0.y, y_);
        z_ = fmaf(v0, x0.z, z_); w_ = fmaf(v0, x0.w, w_);
        x_ = fmaf(v1, x1.x, x_); y_ = fmaf(v1, x1.y, y_);
        z_ = fmaf(v1, x1.z, z_); w_ = fmaf(v1, x1.w, w_);
        x_ = fmaf(v2, x2.x, x_); y_ = fmaf(v2, x2.y, y_);
        z_ = fmaf(v2, x2.z, z_); w_ = fmaf(v2, x2.w, w_);
        x_ = fmaf(v3, x3.x, x_); y_ = fmaf(v3, x3.y, y_);
        z_ = fmaf(v3, x3.z, z_); w_ = fmaf(v3, x3.w, w_);
    };

    // peel to even j so int4 loads are 16B-aligned
    if ((jA & 1) && jA < eA) { scal(jA, aAx, aAy, aAz, aAw); ++jA; }
    if ((jB & 1) && jB < eB) { scal(jB, aBx, aBy, aBz, aBw); ++jB; }

    // joint main loop: 8 independent gathers issued before the 32 FMAs
    for (; jA + 4 <= eA && jB + 4 <= eB; jA += 4, jB += 4) {
        const int4 pa0 = *reinterpret_cast<const int4*>(pairs + jA);
        const int4 pa1 = *reinterpret_cast<const int4*>(pairs + jA + 2);
        const int4 pb0 = *reinterpret_cast<const int4*>(pairs + jB);
        const int4 pb1 = *reinterpret_cast<const int4*>(pairs + jB + 2);
        const float4 xa0 = *reinterpret_cast<const float4*>(X + (size_t)pa0.y * EMB + sub);
        const float4 xa1 = *reinterpret_cast<const float4*>(X + (size_t)pa0.w * EMB + sub);
        const float4 xa2 = *reinterpret_cast<const float4*>(X + (size_t)pa1.y * EMB + sub);
        const float4 xa3 = *reinterpret_cast<const float4*>(X + (size_t)pa1.w * EMB + sub);
        const float4 xb0 = *reinterpret_cast<const float4*>(X + (size_t)pb0.y * EMB + sub);
        const float4 xb1 = *reinterpret_cast<const float4*>(X + (size_t)pb0.w * EMB + sub);
        const float4 xb2 = *reinterpret_cast<const float4*>(X + (size_t)pb1.y * EMB + sub);
        const float4 xb3 = *reinterpret_cast<const float4*>(X + (size_t)pb1.w * EMB + sub);
        const float va0 = __int_as_float(pa0.x), va1 = __int_as_float(pa0.z);
        const float va2 = __int_as_float(pa1.x), va3 = __int_as_float(pa1.z);
        const float vb0 = __int_as_float(pb0.x), vb1 = __int_as_float(pb0.z);
        const float vb2 = __int_as_float(pb1.x), vb3 = __int_as_float(pb1.z);
        aAx = fmaf(va0, xa0.x, aAx); aAy = fmaf(va0, xa0.y, aAy);
        aAz = fmaf(va0, xa0.z, aAz); aAw = fmaf(va0, xa0.w, aAw);
        aAx = fmaf(va1, xa1.x, aAx); aAy = fmaf(va1, xa1.y, aAy);
        aAz = fmaf(va1, xa1.z, aAz); aAw = fmaf(va1, xa1.w, aAw);
        aAx = fmaf(va2, xa2.x, aAx); aAy = fmaf(va2, xa2.y, aAy);
        aAz = fmaf(va2, xa2.z, aAz); aAw = fmaf(va2, xa2.w, aAw);
        aAx = fmaf(va3, xa3.x, aAx); aAy = fmaf(va3, xa3.y, aAy);
        aAz = fmaf(va3, xa3.z, aAz); aAw = fmaf(va3, xa3.w, aAw);
        aBx = fmaf(vb0, xb0.x, aBx); aBy = fmaf(vb0, xb0.y, aBy);
        aBz = fmaf(vb0, xb0.z, aBz); aBw = fmaf(vb0, xb0.w, aBw);
        aBx = fmaf(vb1, xb1.x, aBx); aBy = fmaf(vb1, xb1.y, aBy);
        aBz = fmaf(vb1, xb1.z, aBz); aBw = fmaf(vb1, xb1.w, aBw);
        aBx = fmaf(vb2, xb2.x, aBx); aBy = fmaf(vb2, xb2.y, aBy);
        aBz = fmaf(vb2, xb2.z, aBz); aBw = fmaf(vb2, xb2.w, aBw);
        aBx = fmaf(vb3, xb3.x, aBx); aBy = fmaf(vb3, xb3.y, aBy);
        aBz = fmaf(vb3, xb3.z, aBz); aBw = fmaf(vb3, xb3.w, aBw);
    }
    // drains (short: sorted lengths make |lenA - lenB| small)
    for (; jA + 4 <= eA; jA += 4) quad(jA, aAx, aAy, aAz, aAw);
    for (; jA < eA; ++jA) scal(jA, aAx, aAy, aAz, aAw);
    for (; jB + 4 <= eB; jB += 4) quad(jB, aBx, aBy, aBz, aBw);
    for (; jB < eB; ++jB) scal(jB, aBx, aBy, aBz, aBw);

    const float a = coefs[hop];
    if (rowA >= 0) {
        const size_t o = (size_t)rowA * EMB + sub;
        if (STORE_E)
            *reinterpret_cast<float4*>(Eout + o) = make_float4(aAx, aAy, aAz, aAw);
        if (INIT) {
            *reinterpret_cast<float4*>(Efin + o) =
                make_float4(a * aAx, a * aAy, a * aAz, a * aAw);
        } else {
            float4 f = *reinterpret_cast<const float4*>(Efin + o);
            f.x += a * aAx; f.y += a * aAy; f.z += a * aAz; f.w += a * aAw;
            *reinterpret_cast<float4*>(Efin + o) = f;
        }
    }
    if (rowB >= 0) {
        const size_t o = (size_t)rowB * EMB + sub;
        if (STORE_E)
            *reinterpret_cast<float4*>(Eout + o) = make_float4(aBx, aBy, aBz, aBw);
        if (INIT) {
            *reinterpret_cast<float4*>(Efin + o) =
                make_float4(a * aBx, a * aBy, a * aBz, a * aBw);
        } else {
            float4 f = *reinterpret_cast<const float4*>(Efin + o);
            f.x += a * aBx; f.y += a * aBy; f.z += a * aBz; f.w += a * aBw;
            *reinterpret_cast<float4*>(Efin + o) = f;
        }
    }
}

// ---------------- atomic fallback (if ws too small / n too big) ----------------

__global__ void spmm_atomic_kernel(const float* __restrict__ vals, const int* __restrict__ rows,
                                   const int* __restrict__ cols, int nnz,
                                   const float* __restrict__ X, float* __restrict__ Eout) {
    long long stride = (long long)gridDim.x * blockDim.x;
    long long total = (long long)nnz * 8;
    for (long long t = (long long)blockIdx.x * blockDim.x + threadIdx.x; t < total; t += stride) {
        int i = (int)(t >> 3);
        int sub = ((int)t & 7) * 4;
        float v = vals[i];
        const float4 x = *reinterpret_cast<const float4*>(X + (long long)cols[i] * EMB + sub);
        float* o = Eout + (long long)rows[i] * EMB + sub;
        atomicAdd(o + 0, v * x.x);
        atomicAdd(o + 1, v * x.y);
        atomicAdd(o + 2, v * x.z);
        atomicAdd(o + 3, v * x.w);
    }
}

template <bool INIT>
__global__ void axpy_kernel(const float* __restrict__ E, float* __restrict__ Efin,
                            const float* __restrict__ coefs, int hop, int total4) {
    int i = blockIdx.x * blockDim.x + threadIdx.x;
    if (i >= total4) return;
    float a = coefs[hop];
    float4 e = reinterpret_cast<const float4*>(E)[i];
    if (INIT) {
        reinterpret_cast<float4*>(Efin)[i] = make_float4(a * e.x, a * e.y, a * e.z, a * e.w);
    } else {
        float4 f = reinterpret_cast<float4*>(Efin)[i];
        f.x += a * e.x; f.y += a * e.y; f.z += a * e.z; f.w += a * e.w;
        reinterpret_cast<float4*>(Efin)[i] = f;
    }
}

// ---------------- launch ----------------

extern "C" void kernel_launch(void* const* d_in, const int* in_sizes, int n_in,
                              void* d_out, int out_size, void* d_ws, size_t ws_size,
                              hipStream_t stream) {
    const float* A_vals = (const float*)d_in[0];
    const float* W0     = (const float*)d_in[1];
    const float* alpha  = (const float*)d_in[2];
    const int*   A_rows = (const int*)d_in[3];
    const int*   A_cols = (const int*)d_in[4];
    const int nnz = in_sizes[0];
    const int n   = in_sizes[1] / EMB;
    float* Efin = (float*)d_out;

    char* ws = (char*)d_ws;
    size_t off = 0;
    auto alloc = [&](size_t bytes) -> void* {
        void* p = (void*)(ws + off);
        off += (bytes + 255) & ~(size_t)255;
        return p;
    };

    const int nb = (n + RPB - 1) >> BSHIFT;
    const int nslots = nb << BSHIFT;

    float* Ebuf0 = (float*)alloc((size_t)n * EMB * 4);
    float* Ebuf1 = (float*)alloc((size_t)n * EMB * 4);
    float* coefs = (float*)alloc(4 * sizeof(float));
    int*  rps     = (int*)alloc((size_t)(nslots + 1) * 4);
    int*  order   = (int*)alloc((size_t)nslots * 4);
    int*  bhist   = (int*)alloc(NB * 4);       // contiguous with cursor:
    int*  cursor  = (int*)alloc(NB * 4);       // one 2 KB memset covers both
    int2* pairs   = (int2*)alloc((size_t)nnz * 8);
    size_t off_csr = off;

    int2* pairs_stage = (int2*)Ebuf0;                     // nnz*8 B
    unsigned short* lrow_stage = (unsigned short*)Ebuf1;  // nnz*2 B

    const bool use_csr = (ws_size >= off_csr) && (nb <= NB) && (n <= COLMASK + 1) &&
                         ((size_t)nnz * 8 <= (size_t)n * EMB * 4);

    softmax4_kernel<<<1, 64, 0, stream>>>(alpha, coefs);

    if (use_csr) {
        hipMemsetAsync(bhist, 0, 2 * NB * 4, stream);   // bhist + cursor
        bucket_hist_kernel<<<1024, 256, 0, stream>>>(A_rows, nnz, bhist, nb);
        partition_kernel<<<(nnz + TILE - 1) / TILE, PT_THREADS, 0, stream>>>(
            A_vals, A_rows, A_cols, nnz, bhist, cursor, pairs_stage, lrow_stage);
        bucket_sort_kernel<<<nb, SP_THREADS, 0, stream>>>(
            pairs_stage, lrow_stage, bhist, n, nnz, nb, rps, order, pairs);

        const int groups = (nslots + 1) / 2;
        const int blocks = (groups * 8 + 255) / 256;
        spmm_kernel<true,  true ><<<blocks, 256, 0, stream>>>(rps, order, pairs, W0,    Ebuf0, Efin, coefs, 0, nslots);
        spmm_kernel<false, true ><<<blocks, 256, 0, stream>>>(rps, order, pairs, Ebuf0, Ebuf1, Efin, coefs, 1, nslots);
        spmm_kernel<false, true ><<<blocks, 256, 0, stream>>>(rps, order, pairs, Ebuf1, Ebuf0, Efin, coefs, 2, nslots);
        spmm_kernel<false, false><<<blocks, 256, 0, stream>>>(rps, order, pairs, Ebuf0, Ebuf1, Efin, coefs, 3, nslots);
    } else {
        const float* X = W0;
        float* bufs[2] = {Ebuf0, Ebuf1};
        int total4 = n * EMB / 4;
        int ablocks = (total4 + 255) / 256;
        for (int hop = 0; hop < 4; ++hop) {
            float* Eo = bufs[hop & 1];
            hipMemsetAsync(Eo, 0, (size_t)n * EMB * 4, stream);
            spmm_atomic_kernel<<<2048, 256, 0, stream>>>(A_vals, A_rows, A_cols, nnz, X, Eo);
            if (hop == 0)
                axpy_kernel<true ><<<ablocks, 256, 0, stream>>>(Eo, Efin, coefs, hop, total4);
            else
                axpy_kernel<false><<<ablocks, 256, 0, stream>>>(Eo, Efin, coefs, hop, total4);
            X = Eo;
        }
    }
}

// Round 9
// 511.556 us; speedup vs baseline: 1.0604x; 1.0604x over previous
//
#include <hip/hip_runtime.h>

#define EMB 32
#define BSHIFT 9
#define RPB 512            // rows per bucket = 1 << BSHIFT
#define NB 512             // bucket array size (nb <= NB)
#define TILE 2048
#define PT_THREADS 256
#define PT_ITEMS 8         // TILE / PT_THREADS
#define SP_THREADS 512
#define COLMASK 0x3FFFF    // 18 bits col (n <= 262144); lrow in bits 18..26

// ---------------- CSR build ----------------

__global__ __launch_bounds__(256) void bucket_hist_kernel(
        const int* __restrict__ rows, int nnz, int* __restrict__ bhist, int nb) {
    __shared__ int h[NB];
    const int t = threadIdx.x;
    for (int e = t; e < NB; e += 256) h[e] = 0;
    __syncthreads();
    int stride = gridDim.x * blockDim.x;
    for (int i = blockIdx.x * blockDim.x + t; i < nnz; i += stride)
        atomicAdd(&h[rows[i] >> BSHIFT], 1);
    __syncthreads();
    for (int e = t; e < nb; e += 256)
        if (h[e] > 0) atomicAdd(&bhist[e], h[e]);
}

// Tile-wise partition into bucket-grouped (val, col|lrow<<18) + lrow sidecar.
// 512-entry hists scanned chunked (2 entries/thread). ~25 KB LDS.
__global__ __launch_bounds__(PT_THREADS) void partition_kernel(
        const float* __restrict__ vals, const int* __restrict__ rows,
        const int* __restrict__ cols, int nnz,
        const int* __restrict__ bhist, int* __restrict__ cursor,
        int2* __restrict__ pairs_stage, unsigned short* __restrict__ lrow_stage) {
    __shared__ int h[NB];
    __shared__ int delta[NB];
    __shared__ int partial[PT_THREADS];
    __shared__ float s_val[TILE];
    __shared__ int s_pack[TILE];
    __shared__ unsigned short s_bkt[TILE];
    const int t = threadIdx.x;
    const int e0 = 2 * t, e1 = 2 * t + 1;
    const int tile_start = blockIdx.x * TILE;
    const int tile_cnt = min(TILE, nnz - tile_start);

    // chunked exclusive scan of bhist -> global bucket bases (regs eb0, eb1)
    const int a0 = bhist[e0], a1 = bhist[e1];
    h[e0] = 0; h[e1] = 0;
    partial[t] = a0 + a1;
    __syncthreads();
    for (int off = 1; off < PT_THREADS; off <<= 1) {
        int add = (t >= off) ? partial[t - off] : 0;
        __syncthreads();
        partial[t] += add;
        __syncthreads();
    }
    const int run1 = partial[t] - (a0 + a1);
    const int eb0 = run1, eb1 = run1 + a0;

    // load tile + local bucket hist
    float v[PT_ITEMS];
    int pk[PT_ITEMS], b[PT_ITEMS];
    #pragma unroll
    for (int k = 0; k < PT_ITEMS; ++k) {
        int i = tile_start + t + k * PT_THREADS;
        if (i < nnz) {
            int r = rows[i];
            v[k] = vals[i];
            pk[k] = cols[i] | ((r & (RPB - 1)) << 18);
            b[k] = r >> BSHIFT;
            atomicAdd(&h[b[k]], 1);
        } else {
            b[k] = -1;
        }
    }
    __syncthreads();
    // chunked exclusive scan of tile hist
    const int b0 = h[e0], b1 = h[e1];
    __syncthreads();
    partial[t] = b0 + b1;
    __syncthreads();
    for (int off = 1; off < PT_THREADS; off <<= 1) {
        int add = (t >= off) ? partial[t - off] : 0;
        __syncthreads();
        partial[t] += add;
        __syncthreads();
    }
    const int run2 = partial[t] - (b0 + b1);
    const int excl0 = run2, excl1 = run2 + b0;
    if (b0 > 0) {
        int old = atomicAdd(&cursor[e0], b0);
        delta[e0] = (eb0 + old) - excl0;
    }
    if (b1 > 0) {
        int old = atomicAdd(&cursor[e1], b1);
        delta[e1] = (eb1 + old) - excl1;
    }
    h[e0] = excl0;
    h[e1] = excl1;
    __syncthreads();
    // LDS reorder into bucket-grouped order
    #pragma unroll
    for (int k = 0; k < PT_ITEMS; ++k) {
        if (b[k] >= 0) {
            int rank = atomicAdd(&h[b[k]], 1);
            s_val[rank] = v[k];
            s_pack[rank] = pk[k];
            s_bkt[rank] = (unsigned short)b[k];
        }
    }
    __syncthreads();
    // copy out: consecutive items -> consecutive global slots
    for (int i = t; i < tile_cnt; i += PT_THREADS) {
        int bb = s_bkt[i];
        int gpos = delta[bb] + i;
        int pk_i = s_pack[i];
        pairs_stage[gpos] = make_int2(__float_as_int(s_val[i]), pk_i);
        lrow_stage[gpos] = (unsigned short)(((unsigned)pk_i) >> 18);
    }
}

// Per-bucket counting sort -> row_ptr + final CSR pairs (col stripped of lrow).
__global__ __launch_bounds__(SP_THREADS) void bucket_sort_kernel(
        const int2* __restrict__ pairs_stage, const unsigned short* __restrict__ lrow_stage,
        const int* __restrict__ bhist, int n, int nnz,
        int* __restrict__ row_ptr, int2* __restrict__ pairs) {
    __shared__ int rh[RPB];
    __shared__ int rc[RPB];
    const int bkt = blockIdx.x;
    const int t = threadIdx.x;

    // inclusive scan of bhist (512 entries, 512 threads) -> bucket pair range
    rh[t] = bhist[t];
    __syncthreads();
    for (int off = 1; off < RPB; off <<= 1) {
        int add = (t >= off) ? rh[t - off] : 0;
        __syncthreads();
        rh[t] += add;
        __syncthreads();
    }
    const int i0 = (bkt > 0) ? rh[bkt - 1] : 0;
    const int i1 = rh[bkt];
    __syncthreads();

    const int row0 = bkt << BSHIFT;
    const int nrows = min(RPB, n - row0);
    rh[t] = 0;
    __syncthreads();
    for (int i = i0 + t; i < i1; i += SP_THREADS)
        atomicAdd(&rh[lrow_stage[i]], 1);
    __syncthreads();
    const int own = rh[t];
    for (int off = 1; off < RPB; off <<= 1) {
        int add = (t >= off) ? rh[t - off] : 0;
        __syncthreads();
        rh[t] += add;
        __syncthreads();
    }
    const int excl = rh[t] - own;
    if (t < nrows) row_ptr[row0 + t] = i0 + excl;
    rc[t] = excl;
    if (bkt == 0 && t == 0) row_ptr[n] = nnz;
    __syncthreads();
    for (int i = i0 + t; i < i1; i += SP_THREADS) {
        int2 p = pairs_stage[i];
        int r = lrow_stage[i];
        int pos = i0 + atomicAdd(&rc[r], 1);
        pairs[pos] = make_int2(p.x, p.y & COLMASK);
    }
}

// ---------------- misc ----------------

__global__ void softmax4_kernel(const float* __restrict__ alpha, float* __restrict__ coefs) {
    if (threadIdx.x == 0 && blockIdx.x == 0) {
        float m = fmaxf(fmaxf(alpha[0], alpha[1]), fmaxf(alpha[2], alpha[3]));
        float e0 = __expf(alpha[0] - m), e1 = __expf(alpha[1] - m);
        float e2 = __expf(alpha[2] - m), e3 = __expf(alpha[3] - m);
        float inv = 1.0f / (e0 + e1 + e2 + e3);
        coefs[0] = e0 * inv; coefs[1] = e1 * inv; coefs[2] = e2 * inv; coefs[3] = e3 * inv;
    }
}

// ---------------- CSR SpMM, 4x-unrolled (exact R5 kernel, measured 72 us) ----------------

template <bool INIT, bool STORE_E>
__global__ __launch_bounds__(256) void spmm_kernel(
        const int* __restrict__ row_ptr, const int2* __restrict__ pairs,
        const float* __restrict__ X, float* __restrict__ Eout,
        float* __restrict__ Efin, const float* __restrict__ coefs,
        int hop, int n) {
    int tid = blockIdx.x * blockDim.x + threadIdx.x;
    int row = tid >> 3;
    if (row >= n) return;
    const int sub = (tid & 7) * 4;
    int j = row_ptr[row];
    const int j1 = row_ptr[row + 1];
    float ax = 0.f, ay = 0.f, az = 0.f, aw = 0.f;

    if ((j & 1) && j < j1) {
        int2 p = pairs[j];
        float v = __int_as_float(p.x);
        const float4 x = *reinterpret_cast<const float4*>(X + (size_t)p.y * EMB + sub);
        ax = fmaf(v, x.x, ax); ay = fmaf(v, x.y, ay);
        az = fmaf(v, x.z, az); aw = fmaf(v, x.w, aw);
        ++j;
    }
    for (; j + 4 <= j1; j += 4) {
        const int4 pa = *reinterpret_cast<const int4*>(pairs + j);
        const int4 pb = *reinterpret_cast<const int4*>(pairs + j + 2);
        const float4 x0 = *reinterpret_cast<const float4*>(X + (size_t)pa.y * EMB + sub);
        const float4 x1 = *reinterpret_cast<const float4*>(X + (size_t)pa.w * EMB + sub);
        const float4 x2 = *reinterpret_cast<const float4*>(X + (size_t)pb.y * EMB + sub);
        const float4 x3 = *reinterpret_cast<const float4*>(X + (size_t)pb.w * EMB + sub);
        const float v0 = __int_as_float(pa.x), v1 = __int_as_float(pa.z);
        const float v2 = __int_as_float(pb.x), v3 = __int_as_float(pb.z);
        ax = fmaf(v0, x0.x, ax); ay = fmaf(v0, x0.y, ay);
        az = fmaf(v0, x0.z, az); aw = fmaf(v0, x0.w, aw);
        ax = fmaf(v1, x1.x, ax); ay = fmaf(v1, x1.y, ay);
        az = fmaf(v1, x1.z, az); aw = fmaf(v1, x1.w, aw);
        ax = fmaf(v2, x2.x, ax); ay = fmaf(v2, x2.y, ay);
        az = fmaf(v2, x2.z, az); aw = fmaf(v2, x2.w, aw);
        ax = fmaf(v3, x3.x, ax); ay = fmaf(v3, x3.y, ay);
        az = fmaf(v3, x3.z, az); aw = fmaf(v3, x3.w, aw);
    }
    for (; j < j1; ++j) {
        int2 p = pairs[j];
        float v = __int_as_float(p.x);
        const float4 x = *reinterpret_cast<const float4*>(X + (size_t)p.y * EMB + sub);
        ax = fmaf(v, x.x, ax); ay = fmaf(v, x.y, ay);
        az = fmaf(v, x.z, az); aw = fmaf(v, x.w, aw);
    }

    const size_t o = (size_t)row * EMB + sub;
    if (STORE_E)
        *reinterpret_cast<float4*>(Eout + o) = make_float4(ax, ay, az, aw);
    const float a = coefs[hop];
    if (INIT) {
        *reinterpret_cast<float4*>(Efin + o) = make_float4(a * ax, a * ay, a * az, a * aw);
    } else {
        float4 f = *reinterpret_cast<const float4*>(Efin + o);
        f.x += a * ax; f.y += a * ay; f.z += a * az; f.w += a * aw;
        *reinterpret_cast<float4*>(Efin + o) = f;
    }
}

// ---------------- atomic fallback (if ws too small / n too big) ----------------

__global__ void spmm_atomic_kernel(const float* __restrict__ vals, const int* __restrict__ rows,
                                   const int* __restrict__ cols, int nnz,
                                   const float* __restrict__ X, float* __restrict__ Eout) {
    long long stride = (long long)gridDim.x * blockDim.x;
    long long total = (long long)nnz * 8;
    for (long long t = (long long)blockIdx.x * blockDim.x + threadIdx.x; t < total; t += stride) {
        int i = (int)(t >> 3);
        int sub = ((int)t & 7) * 4;
        float v = vals[i];
        const float4 x = *reinterpret_cast<const float4*>(X + (long long)cols[i] * EMB + sub);
        float* o = Eout + (long long)rows[i] * EMB + sub;
        atomicAdd(o + 0, v * x.x);
        atomicAdd(o + 1, v * x.y);
        atomicAdd(o + 2, v * x.z);
        atomicAdd(o + 3, v * x.w);
    }
}

template <bool INIT>
__global__ void axpy_kernel(const float* __restrict__ E, float* __restrict__ Efin,
                            const float* __restrict__ coefs, int hop, int total4) {
    int i = blockIdx.x * blockDim.x + threadIdx.x;
    if (i >= total4) return;
    float a = coefs[hop];
    float4 e = reinterpret_cast<const float4*>(E)[i];
    if (INIT) {
        reinterpret_cast<float4*>(Efin)[i] = make_float4(a * e.x, a * e.y, a * e.z, a * e.w);
    } else {
        float4 f = reinterpret_cast<float4*>(Efin)[i];
        f.x += a * e.x; f.y += a * e.y; f.z += a * e.z; f.w += a * e.w;
        reinterpret_cast<float4*>(Efin)[i] = f;
    }
}

// ---------------- launch ----------------

extern "C" void kernel_launch(void* const* d_in, const int* in_sizes, int n_in,
                              void* d_out, int out_size, void* d_ws, size_t ws_size,
                              hipStream_t stream) {
    const float* A_vals = (const float*)d_in[0];
    const float* W0     = (const float*)d_in[1];
    const float* alpha  = (const float*)d_in[2];
    const int*   A_rows = (const int*)d_in[3];
    const int*   A_cols = (const int*)d_in[4];
    const int nnz = in_sizes[0];
    const int n   = in_sizes[1] / EMB;
    float* Efin = (float*)d_out;

    char* ws = (char*)d_ws;
    size_t off = 0;
    auto alloc = [&](size_t bytes) -> void* {
        void* p = (void*)(ws + off);
        off += (bytes + 255) & ~(size_t)255;
        return p;
    };

    float* Ebuf0 = (float*)alloc((size_t)n * EMB * 4);
    float* Ebuf1 = (float*)alloc((size_t)n * EMB * 4);
    float* coefs = (float*)alloc(4 * sizeof(float));
    int*  row_ptr = (int*)alloc((size_t)(n + 1) * 4);
    int*  bhist   = (int*)alloc(NB * 4);       // contiguous with cursor:
    int*  cursor  = (int*)alloc(NB * 4);       // one 4 KB memset covers both
    int2* pairs   = (int2*)alloc((size_t)nnz * 8);
    size_t off_csr = off;

    int2* pairs_stage = (int2*)Ebuf0;                     // nnz*8 B
    unsigned short* lrow_stage = (unsigned short*)Ebuf1;  // nnz*2 B

    const int nb = (n + RPB - 1) >> BSHIFT;
    const bool use_csr = (ws_size >= off_csr) && (nb <= NB) && (n <= COLMASK + 1) &&
                         ((size_t)nnz * 8 <= (size_t)n * EMB * 4);

    softmax4_kernel<<<1, 64, 0, stream>>>(alpha, coefs);

    if (use_csr) {
        hipMemsetAsync(bhist, 0, 2 * NB * 4, stream);   // bhist + cursor
        bucket_hist_kernel<<<512, 256, 0, stream>>>(A_rows, nnz, bhist, nb);
        partition_kernel<<<(nnz + TILE - 1) / TILE, PT_THREADS, 0, stream>>>(
            A_vals, A_rows, A_cols, nnz, bhist, cursor, pairs_stage, lrow_stage);
        bucket_sort_kernel<<<nb, SP_THREADS, 0, stream>>>(
            pairs_stage, lrow_stage, bhist, n, nnz, row_ptr, pairs);

        int blocks = (n * 8 + 255) / 256;
        spmm_kernel<true,  true ><<<blocks, 256, 0, stream>>>(row_ptr, pairs, W0,    Ebuf0, Efin, coefs, 0, n);
        spmm_kernel<false, true ><<<blocks, 256, 0, stream>>>(row_ptr, pairs, Ebuf0, Ebuf1, Efin, coefs, 1, n);
        spmm_kernel<false, true ><<<blocks, 256, 0, stream>>>(row_ptr, pairs, Ebuf1, Ebuf0, Efin, coefs, 2, n);
        spmm_kernel<false, false><<<blocks, 256, 0, stream>>>(row_ptr, pairs, Ebuf0, Ebuf1, Efin, coefs, 3, n);
    } else {
        const float* X = W0;
        float* bufs[2] = {Ebuf0, Ebuf1};
        int total4 = n * EMB / 4;
        int ablocks = (total4 + 255) / 256;
        for (int hop = 0; hop < 4; ++hop) {
            float* Eo = bufs[hop & 1];
            hipMemsetAsync(Eo, 0, (size_t)n * EMB * 4, stream);
            spmm_atomic_kernel<<<2048, 256, 0, stream>>>(A_vals, A_rows, A_cols, nnz, X, Eo);
            if (hop == 0)
                axpy_kernel<true ><<<ablocks, 256, 0, stream>>>(Eo, Efin, coefs, hop, total4);
            else
                axpy_kernel<false><<<ablocks, 256, 0, stream>>>(Eo, Efin, coefs, hop, total4);
            X = Eo;
        }
    }
}